// Round 10
// baseline (266.204 us; speedup 1.0000x reference)
//
#include <hip/hip_runtime.h>

#define NB 16
#define NC 256
#define HW 2304
#define CHW 589824  // NC*HW

typedef __attribute__((ext_vector_type(8))) short bf16x8;
typedef __attribute__((ext_vector_type(16))) float f32x16;

union BF8 { bf16x8 v; unsigned short u[8]; };

__device__ inline unsigned short f2bf(float f) {
  unsigned u = __builtin_bit_cast(unsigned, f);
  u += 0x7fffu + ((u >> 16) & 1u);  // RNE (inputs finite)
  return (unsigned short)(u >> 16);
}

// ================= K1: prep (wpack + x1pack + xtpack), role-switched — R9-proven =================
// wp[rt][f][l][j]      = W[32rt + (l&31)][16f + 8*(l>>5) + j]
// x1p[b][nb][f][l][j]  = v[(32nb + (l&31))*256 + 16f + 8*(l>>5) + j]   (+ sumsq partials)
// xtp[b][mb][f][l][j]  = x[b][k = 16f+8*(l>>5)+j][m = 32mb + (l&31)]
__global__ __launch_bounds__(256) void prep_kernel(const float* __restrict__ x,
                                                   const float* __restrict__ W,
                                                   unsigned short* __restrict__ wp,
                                                   unsigned short* __restrict__ x1p,
                                                   unsigned short* __restrict__ xtp,
                                                   double* __restrict__ partials) {
  __shared__ __align__(16) char smem[33344];
  const int bid = blockIdx.x;
  const int tid = threadIdx.x;

  if (bid < 8) {  // ---- wpack, rt = bid ----
    const int rt = bid;
    float* tile = (float*)smem;  // [32][260]
    const float4* src = (const float4*)(W + (size_t)rt * 32 * 256);
    #pragma unroll
    for (int it = 0; it < 8; ++it) {
      const int i = tid + 256 * it;
      float4 v = src[i];
      const int fi = 4 * i, row = fi >> 8, col = fi & 255;
      *(float4*)&tile[row * 260 + col] = v;
    }
    __syncthreads();
    const int w = tid >> 6, l = tid & 63, l31 = l & 31, h = l >> 5;
    unsigned short* dst = wp + (size_t)rt * 8192;
    #pragma unroll
    for (int ff = 0; ff < 4; ++ff) {
      const int f = 4 * w + ff;
      const float* rp = &tile[l31 * 260 + 16 * f + 8 * h];
      const float4 r0 = *(const float4*)rp;
      const float4 r1 = *(const float4*)(rp + 4);
      BF8 o;
      o.u[0] = f2bf(r0.x); o.u[1] = f2bf(r0.y); o.u[2] = f2bf(r0.z); o.u[3] = f2bf(r0.w);
      o.u[4] = f2bf(r1.x); o.u[5] = f2bf(r1.y); o.u[6] = f2bf(r1.z); o.u[7] = f2bf(r1.w);
      *(bf16x8*)(dst + (((size_t)f) * 64 + l) * 8) = o.v;
    }
  } else if (bid < 8 + 1152) {  // ---- x1pack + sumsq ----
    const int e = bid - 8;
    const int nb = e % 72, b = e / 72;
    float* tile = (float*)smem;              // [32][260]
    double* red = (double*)(smem + 33280);   // [4]
    const float4* src = (const float4*)(x + (size_t)b * CHW + nb * 8192);
    double ss = 0.0;
    #pragma unroll
    for (int it = 0; it < 8; ++it) {
      const int i = tid + 256 * it;
      float4 v = src[i];
      const int fi = 4 * i, row = fi >> 8, col = fi & 255;
      *(float4*)&tile[row * 260 + col] = v;
      ss += (double)v.x * v.x + (double)v.y * v.y + (double)v.z * v.z + (double)v.w * v.w;
    }
    #pragma unroll
    for (int off = 32; off > 0; off >>= 1) ss += __shfl_down(ss, off, 64);
    const int w = tid >> 6, l = tid & 63;
    if (l == 0) red[w] = ss;
    __syncthreads();
    if (tid == 0) partials[b * 72 + nb] = red[0] + red[1] + red[2] + red[3];
    const int l31 = l & 31, h = l >> 5;
    unsigned short* dst = x1p + (size_t)b * CHW + (size_t)nb * 8192;
    #pragma unroll
    for (int ff = 0; ff < 4; ++ff) {
      const int f = 4 * w + ff;
      const float* rp = &tile[l31 * 260 + 16 * f + 8 * h];
      const float4 r0 = *(const float4*)rp;
      const float4 r1 = *(const float4*)(rp + 4);
      BF8 o;
      o.u[0] = f2bf(r0.x); o.u[1] = f2bf(r0.y); o.u[2] = f2bf(r0.z); o.u[3] = f2bf(r0.w);
      o.u[4] = f2bf(r1.x); o.u[5] = f2bf(r1.y); o.u[6] = f2bf(r1.z); o.u[7] = f2bf(r1.w);
      *(bf16x8*)(dst + (((size_t)f) * 64 + l) * 8) = o.v;
    }
  } else {  // ---- xtpack ----
    const int e = bid - 1160;
    const int mt = e % 36, kt = (e / 36) % 4, b = e / 144;
    const int m0 = mt * 64, k0 = kt * 64;
    float* tile = (float*)smem;  // [64][68]
    const float* xb = x + (size_t)b * CHW;
    #pragma unroll
    for (int it = 0; it < 4; ++it) {
      const int i = tid + 256 * it;
      const int row = i >> 4, c4 = (i & 15) * 4;
      float4 v = *(const float4*)(xb + (size_t)(k0 + row) * HW + m0 + c4);
      *(float4*)&tile[row * 68 + c4] = v;
    }
    __syncthreads();
    const int w = tid >> 6, l = tid & 63, l31 = l & 31, h = l >> 5;
    unsigned short* dst = xtp + (size_t)b * CHW;
    #pragma unroll
    for (int pp = 0; pp < 2; ++pp) {
      const int p = 2 * w + pp, mbl = p >> 2, fl = p & 3;
      BF8 o;
      #pragma unroll
      for (int j = 0; j < 8; ++j)
        o.u[j] = f2bf(tile[(16 * fl + 8 * h + j) * 68 + 32 * mbl + l31]);
      const int mb = 2 * mt + mbl, f = 4 * kt + fl;
      *(bf16x8*)(dst + (((size_t)mb * 16 + f) * 64 + l) * 8) = o.v;
    }
  }
}

// ================= K2: conv2 — conv + trpack fused, 512 threads (8 waves) — R9-proven =================
// Reshape identity: reshaped (m,c) = storage (c'=m/9, m'=256*(m%9)+c); block (b,rt) owns
// reshaped rows [288rt, 288rt+288) completely -> coalesced 16B/lane trp writes.
__global__ __launch_bounds__(512, 1) void conv2_kernel(const unsigned short* __restrict__ wp,
                                                       const float* __restrict__ bias,
                                                       const unsigned short* __restrict__ xtp,
                                                       unsigned short* __restrict__ trp,
                                                       const double* __restrict__ partials,
                                                       float* __restrict__ inv_xn2) {
  const int bid = blockIdx.x;
  if (bid == 128) {  // ---- finish role: 1/xn^2 per batch (indep. of conv output) ----
    const int t = threadIdx.x;
    if (t >= 256) return;
    const int b = t >> 4, i0 = t & 15;
    double v = 0.0;
    for (int i = i0; i < 72; i += 16) v += partials[b * 72 + i];
    v += __shfl_down(v, 8, 64);
    v += __shfl_down(v, 4, 64);
    v += __shfl_down(v, 2, 64);
    v += __shfl_down(v, 1, 64);
    if (i0 == 0) inv_xn2[b] = (float)(1.0 / v);
    return;
  }
  const int xcd = bid & 7, q = bid >> 3;     // q in [0,16)
  const int b = xcd + 8 * (q & 1);           // 2 batches per XCD -> xtp[b] L2-resident
  const int rt = q >> 1;                     // [0,8) c'-row tile of 32
  const int tid = threadIdx.x, w = tid >> 6, l = tid & 63, l31 = l & 31, h = l >> 5;
  const unsigned short* xb = xtp + (size_t)b * CHW;

  __shared__ unsigned short tile[32 * 2312];  // [c'_local][m' + pad8]

  // A-frags: W rows 32rt..32rt+31, all K (shared by all waves)
  bf16x8 af[16];
  #pragma unroll
  for (int f = 0; f < 16; ++f)
    af[f] = *(const bf16x8*)(wp + (((size_t)rt * 16 + f) * 64 + l) * 8);
  // bias per accumulator register
  float bcol[16];
  #pragma unroll
  for (int reg = 0; reg < 16; ++reg) {
    const int rowl = (reg & 3) + 8 * (reg >> 2) + 4 * h;
    bcol[reg] = bias[32 * rt + rowl];
  }

  // ---- MFMA phase: wave w covers xtp-mb in [9w, 9w+9) (288 m' each) ----
  for (int i = 0; i < 9; ++i) {
    const int mb = 9 * w + i;
    f32x16 acc;
    #pragma unroll
    for (int r = 0; r < 16; ++r) acc[r] = 0.f;
    #pragma unroll
    for (int f = 0; f < 16; ++f) {
      bf16x8 bv = *(const bf16x8*)(xb + (((size_t)mb * 16 + f) * 64 + l) * 8);
      acc = __builtin_amdgcn_mfma_f32_32x32x16_bf16(af[f], bv, acc, 0, 0, 0);
    }
    #pragma unroll
    for (int reg = 0; reg < 16; ++reg) {
      const int rowl = (reg & 3) + 8 * (reg >> 2) + 4 * h;
      tile[rowl * 2312 + mb * 32 + l31] = f2bf(acc[reg] + bcol[reg]);
    }
  }
  __syncthreads();

  // ---- emission phase: 144 subblocks (kfi in [0,18), cb8 in [0,8)), 18 per wave ----
  unsigned short* tb = trp + (size_t)b * CHW;
  for (int si = 0; si < 18; ++si) {
    const int id = 18 * w + si;
    const int kfi = id >> 3, cb8 = id & 7;
    const int mbase = 288 * rt + 16 * kfi;     // 16-aligned reshaped-row base
    const int mb2 = mbase >> 6, kf = (mbase >> 4) & 3;
    BF8 o;
    #pragma unroll
    for (int j = 0; j < 8; ++j) {
      const int m = mbase + 8 * h + j;         // reshaped row
      const int a = m / 9, s = m - 9 * a;      // c' = a, m' = 256s + c
      o.u[j] = tile[(a - 32 * rt) * 2312 + 256 * s + 32 * cb8 + l31];
    }
    *(bf16x8*)(tb + (size_t)mb2 * 16384 + (((size_t)cb8 * 4 + kf) * 64 + l) * 8) = o.v;
  }
}

// ================= K4: fused v9 — n-tile 128, 512 thr, 4x B-frag reuse (L2-traffic halved) =================
// R9 diagnosis: per-wave 32 KB L2 loads per chunk for 64 MFMAs -> 256 KB/CU/chunk at ~38 B/cy
// = ~7K cy/chunk, matching the observed wall. Fix: 4 n-panels per block; every bv/bt fragment
// feeds 4 MFMAs (was 2). 9 chunks of 256 m; wave c owns 32 S-m-cols + 32 Y-c'-cols.
// LDS = Af 64 KB + single Pl[128][264] 67.6 KB = 133 KB (1 block/CU, 8 waves).
// Regs: s0-3(64) + yacc[4](64 acc) + bt[16](64) ~ 212 under LB(512,2)=256 budget -- no forced
// occupancy (R8 lesson), no scheduling primitives (R3/R4 lesson), point-of-use bv (no NXT
// prefetch: doesn't fit regs and drains at the barrier anyway, R3).
// Barrier-A/B single-Pl ordering correctness-proven in R8.
__global__ __launch_bounds__(512, 2) void fused_kernel(const unsigned short* __restrict__ x1p,
                                                       const unsigned short* __restrict__ xtp,
                                                       const unsigned short* __restrict__ trp,
                                                       const float* __restrict__ inv_xn2,
                                                       float* __restrict__ out) {
  const int bid = blockIdx.x;                // 288 blocks
  const int xcd = bid & 7, j = bid >> 3;     // j in [0,36)
  const int hi = (j >= 18) ? 1 : 0;
  const int b = xcd + 8 * hi;                // one batch per XCD at a time
  const int nt = j - 18 * hi;                // [0,18) n-tile of 128 rows
  const unsigned short* x1b = x1p + (size_t)b * CHW + (size_t)nt * 32768;  // 4 nb blocks
  const unsigned short* xtb = xtp + (size_t)b * CHW;
  const unsigned short* ttb = trp + (size_t)b * CHW;
  float* ob = out + (size_t)b * CHW;
  const float inv2 = inv_xn2[b];

  const int tid = threadIdx.x;
  const int c = tid >> 6, lane = tid & 63;   // 8 waves; c = S-m-col / Y-c'-col group
  const int l31 = lane & 31, h = lane >> 5;

  __shared__ unsigned short Af[32768];       // 4 n-panels x 16 A-frags x 512 shorts (64 KB)
  __shared__ unsigned short Pl[128][264];    // single-buffered S chunk 128n x 256m (+8 pad)

  {  // stage all 4 n-panels' A-frags (coalesced 16B): 4096 uint4, 512 thr x 8
    const uint4* gsrc = (const uint4*)x1b;
    uint4* ldst = (uint4*)Af;
    #pragma unroll
    for (int it = 0; it < 8; ++it) ldst[tid + 512 * it] = gsrc[tid + 512 * it];
  }
  __syncthreads();

  f32x16 yacc[4];  // [n-panel] x (32n x 32c')
  #pragma unroll
  for (int nh = 0; nh < 4; ++nh)
    #pragma unroll
    for (int i = 0; i < 16; ++i) yacc[nh][i] = 0.f;

  for (int ch = 0; ch < 9; ++ch) {
    // ---- S phase: wave c covers m-cols [32*(8ch+c), +32); 4 independent nh chains ----
    f32x16 s0, s1, s2, s3;
    #pragma unroll
    for (int i = 0; i < 16; ++i) { s0[i] = 0.f; s1[i] = 0.f; s2[i] = 0.f; s3[i] = 0.f; }
    const unsigned short* bp = xtb + (size_t)(8 * ch + c) * 8192 + lane * 8;
    #pragma unroll
    for (int f = 0; f < 16; ++f) {
      bf16x8 bv = *(const bf16x8*)(bp + f * 512);
      bf16x8 a0 = *(const bf16x8*)(Af + (size_t)f * 512 + lane * 8);
      bf16x8 a1 = *(const bf16x8*)(Af + (size_t)(16 + f) * 512 + lane * 8);
      bf16x8 a2 = *(const bf16x8*)(Af + (size_t)(32 + f) * 512 + lane * 8);
      bf16x8 a3 = *(const bf16x8*)(Af + (size_t)(48 + f) * 512 + lane * 8);
      s0 = __builtin_amdgcn_mfma_f32_32x32x16_bf16(a0, bv, s0, 0, 0, 0);
      s1 = __builtin_amdgcn_mfma_f32_32x32x16_bf16(a1, bv, s1, 0, 0, 0);
      s2 = __builtin_amdgcn_mfma_f32_32x32x16_bf16(a2, bv, s2, 0, 0, 0);
      s3 = __builtin_amdgcn_mfma_f32_32x32x16_bf16(a3, bv, s3, 0, 0, 0);
    }
    // ---- Y B-frags for this chunk (independent of Pl; land during P + barriers) ----
    bf16x8 bt[16];
    #pragma unroll
    for (int kk = 0; kk < 16; ++kk) {
      const size_t mb_ = 4 * ch + (kk >> 2);
      bt[kk] = *(const bf16x8*)(ttb + mb_ * 16384 + ((size_t)(c * 4 + (kk & 3))) * 512 + lane * 8);
    }
    // ---- P = relu(s*inv2)^2 in regs (rides across barrier-A) ----
    #pragma unroll
    for (int i = 0; i < 16; ++i) {
      float v0 = fmaxf(s0[i] * inv2, 0.f); s0[i] = v0 * v0;
      float v1 = fmaxf(s1[i] * inv2, 0.f); s1[i] = v1 * v1;
      float v2 = fmaxf(s2[i] * inv2, 0.f); s2[i] = v2 * v2;
      float v3 = fmaxf(s3[i] * inv2, 0.f); s3[i] = v3 * v3;
    }
    __syncthreads();  // barrier-A: all waves done reading Pl from previous chunk
    #pragma unroll
    for (int reg = 0; reg < 16; ++reg) {
      const int rowp = (reg & 3) + 8 * (reg >> 2) + 4 * h;
      Pl[rowp][32 * c + l31]      = f2bf(s0[reg]);
      Pl[32 + rowp][32 * c + l31] = f2bf(s1[reg]);
      Pl[64 + rowp][32 * c + l31] = f2bf(s2[reg]);
      Pl[96 + rowp][32 * c + l31] = f2bf(s3[reg]);
    }
    __syncthreads();  // barrier-B: Pl visible
    // ---- Y phase: 64 MFMAs/wave, 4 chains; each bt frag feeds 4 MFMAs ----
    #pragma unroll
    for (int kk = 0; kk < 16; ++kk) {
      bf16x8 p0 = *(const bf16x8*)&Pl[l31][16 * kk + 8 * h];
      bf16x8 p1 = *(const bf16x8*)&Pl[32 + l31][16 * kk + 8 * h];
      bf16x8 p2 = *(const bf16x8*)&Pl[64 + l31][16 * kk + 8 * h];
      bf16x8 p3 = *(const bf16x8*)&Pl[96 + l31][16 * kk + 8 * h];
      yacc[0] = __builtin_amdgcn_mfma_f32_32x32x16_bf16(p0, bt[kk], yacc[0], 0, 0, 0);
      yacc[1] = __builtin_amdgcn_mfma_f32_32x32x16_bf16(p1, bt[kk], yacc[1], 0, 0, 0);
      yacc[2] = __builtin_amdgcn_mfma_f32_32x32x16_bf16(p2, bt[kk], yacc[2], 0, 0, 0);
      yacc[3] = __builtin_amdgcn_mfma_f32_32x32x16_bf16(p3, bt[kk], yacc[3], 0, 0, 0);
    }
  }

  // ---- epilogue: out flat at ob[n*256 + k'] ----
  #pragma unroll
  for (int nh = 0; nh < 4; ++nh)
    #pragma unroll
    for (int reg = 0; reg < 16; ++reg) {
      const int rowp = (reg & 3) + 8 * (reg >> 2) + 4 * h;
      ob[(size_t)(128 * nt + 32 * nh + rowp) * NC + 32 * c + l31] = yacc[nh][reg];
    }
}

extern "C" void kernel_launch(void* const* d_in, const int* in_sizes, int n_in,
                              void* d_out, int out_size, void* d_ws, size_t ws_size,
                              hipStream_t stream) {
  const float* x    = (const float*)d_in[0];
  const float* W    = (const float*)d_in[1];
  const float* bias = (const float*)d_in[2];
  float* out = (float*)d_out;

  const size_t SZ = (size_t)NB * CHW * sizeof(unsigned short);  // 18,874,368 B
  double* partials       = (double*)d_ws;                           // 9216 B used
  float* inv_xn2         = (float*)((char*)d_ws + 16384);
  unsigned short* wp     = (unsigned short*)((char*)d_ws + 32768);  // 128 KB
  unsigned short* x1p    = (unsigned short*)((char*)d_ws + 163840);
  unsigned short* xtp    = (unsigned short*)((char*)d_ws + 163840 + SZ);
  unsigned short* trp    = (unsigned short*)((char*)d_ws + 163840 + 3 * SZ);

  prep_kernel<<<3464, 256, 0, stream>>>(x, W, wp, x1p, xtp, partials);
  conv2_kernel<<<129, 512, 0, stream>>>(wp, bias, xtp, trp, partials, inv_xn2);
  fused_kernel<<<288, 512, 0, stream>>>(x1p, xtp, trp, inv_xn2, out);
}

// Round 11
// 237.373 us; speedup vs baseline: 1.1215x; 1.1215x over previous
//
#include <hip/hip_runtime.h>

#define NB 16
#define NC 256
#define HW 2304
#define CHW 589824  // NC*HW

typedef __attribute__((ext_vector_type(8))) short bf16x8;
typedef __attribute__((ext_vector_type(16))) float f32x16;

union BF8 { bf16x8 v; unsigned short u[8]; };

__device__ inline unsigned short f2bf(float f) {
  unsigned u = __builtin_bit_cast(unsigned, f);
  u += 0x7fffu + ((u >> 16) & 1u);  // RNE (inputs finite)
  return (unsigned short)(u >> 16);
}

// ================= K1: prep (wpack + x1pack + xtpack), role-switched — R9-proven =================
// wp[rt][f][l][j]      = W[32rt + (l&31)][16f + 8*(l>>5) + j]
// x1p[b][nb][f][l][j]  = v[(32nb + (l&31))*256 + 16f + 8*(l>>5) + j]   (+ sumsq partials)
// xtp[b][mb][f][l][j]  = x[b][k = 16f+8*(l>>5)+j][m = 32mb + (l&31)]
__global__ __launch_bounds__(256) void prep_kernel(const float* __restrict__ x,
                                                   const float* __restrict__ W,
                                                   unsigned short* __restrict__ wp,
                                                   unsigned short* __restrict__ x1p,
                                                   unsigned short* __restrict__ xtp,
                                                   double* __restrict__ partials) {
  __shared__ __align__(16) char smem[33344];
  const int bid = blockIdx.x;
  const int tid = threadIdx.x;

  if (bid < 8) {  // ---- wpack, rt = bid ----
    const int rt = bid;
    float* tile = (float*)smem;  // [32][260]
    const float4* src = (const float4*)(W + (size_t)rt * 32 * 256);
    #pragma unroll
    for (int it = 0; it < 8; ++it) {
      const int i = tid + 256 * it;
      float4 v = src[i];
      const int fi = 4 * i, row = fi >> 8, col = fi & 255;
      *(float4*)&tile[row * 260 + col] = v;
    }
    __syncthreads();
    const int w = tid >> 6, l = tid & 63, l31 = l & 31, h = l >> 5;
    unsigned short* dst = wp + (size_t)rt * 8192;
    #pragma unroll
    for (int ff = 0; ff < 4; ++ff) {
      const int f = 4 * w + ff;
      const float* rp = &tile[l31 * 260 + 16 * f + 8 * h];
      const float4 r0 = *(const float4*)rp;
      const float4 r1 = *(const float4*)(rp + 4);
      BF8 o;
      o.u[0] = f2bf(r0.x); o.u[1] = f2bf(r0.y); o.u[2] = f2bf(r0.z); o.u[3] = f2bf(r0.w);
      o.u[4] = f2bf(r1.x); o.u[5] = f2bf(r1.y); o.u[6] = f2bf(r1.z); o.u[7] = f2bf(r1.w);
      *(bf16x8*)(dst + (((size_t)f) * 64 + l) * 8) = o.v;
    }
  } else if (bid < 8 + 1152) {  // ---- x1pack + sumsq ----
    const int e = bid - 8;
    const int nb = e % 72, b = e / 72;
    float* tile = (float*)smem;              // [32][260]
    double* red = (double*)(smem + 33280);   // [4]
    const float4* src = (const float4*)(x + (size_t)b * CHW + nb * 8192);
    double ss = 0.0;
    #pragma unroll
    for (int it = 0; it < 8; ++it) {
      const int i = tid + 256 * it;
      float4 v = src[i];
      const int fi = 4 * i, row = fi >> 8, col = fi & 255;
      *(float4*)&tile[row * 260 + col] = v;
      ss += (double)v.x * v.x + (double)v.y * v.y + (double)v.z * v.z + (double)v.w * v.w;
    }
    #pragma unroll
    for (int off = 32; off > 0; off >>= 1) ss += __shfl_down(ss, off, 64);
    const int w = tid >> 6, l = tid & 63;
    if (l == 0) red[w] = ss;
    __syncthreads();
    if (tid == 0) partials[b * 72 + nb] = red[0] + red[1] + red[2] + red[3];
    const int l31 = l & 31, h = l >> 5;
    unsigned short* dst = x1p + (size_t)b * CHW + (size_t)nb * 8192;
    #pragma unroll
    for (int ff = 0; ff < 4; ++ff) {
      const int f = 4 * w + ff;
      const float* rp = &tile[l31 * 260 + 16 * f + 8 * h];
      const float4 r0 = *(const float4*)rp;
      const float4 r1 = *(const float4*)(rp + 4);
      BF8 o;
      o.u[0] = f2bf(r0.x); o.u[1] = f2bf(r0.y); o.u[2] = f2bf(r0.z); o.u[3] = f2bf(r0.w);
      o.u[4] = f2bf(r1.x); o.u[5] = f2bf(r1.y); o.u[6] = f2bf(r1.z); o.u[7] = f2bf(r1.w);
      *(bf16x8*)(dst + (((size_t)f) * 64 + l) * 8) = o.v;
    }
  } else {  // ---- xtpack ----
    const int e = bid - 1160;
    const int mt = e % 36, kt = (e / 36) % 4, b = e / 144;
    const int m0 = mt * 64, k0 = kt * 64;
    float* tile = (float*)smem;  // [64][68]
    const float* xb = x + (size_t)b * CHW;
    #pragma unroll
    for (int it = 0; it < 4; ++it) {
      const int i = tid + 256 * it;
      const int row = i >> 4, c4 = (i & 15) * 4;
      float4 v = *(const float4*)(xb + (size_t)(k0 + row) * HW + m0 + c4);
      *(float4*)&tile[row * 68 + c4] = v;
    }
    __syncthreads();
    const int w = tid >> 6, l = tid & 63, l31 = l & 31, h = l >> 5;
    unsigned short* dst = xtp + (size_t)b * CHW;
    #pragma unroll
    for (int pp = 0; pp < 2; ++pp) {
      const int p = 2 * w + pp, mbl = p >> 2, fl = p & 3;
      BF8 o;
      #pragma unroll
      for (int j = 0; j < 8; ++j)
        o.u[j] = f2bf(tile[(16 * fl + 8 * h + j) * 68 + 32 * mbl + l31]);
      const int mb = 2 * mt + mbl, f = 4 * kt + fl;
      *(bf16x8*)(dst + (((size_t)mb * 16 + f) * 64 + l) * 8) = o.v;
    }
  }
}

// ================= K2: conv2 — conv + trpack fused, 512 threads (8 waves) — R9-proven =================
// Reshape identity: reshaped (m,c) = storage (c'=m/9, m'=256*(m%9)+c); block (b,rt) owns
// reshaped rows [288rt, 288rt+288) completely -> coalesced 16B/lane trp writes.
__global__ __launch_bounds__(512, 1) void conv2_kernel(const unsigned short* __restrict__ wp,
                                                       const float* __restrict__ bias,
                                                       const unsigned short* __restrict__ xtp,
                                                       unsigned short* __restrict__ trp,
                                                       const double* __restrict__ partials,
                                                       float* __restrict__ inv_xn2) {
  const int bid = blockIdx.x;
  if (bid == 128) {  // ---- finish role: 1/xn^2 per batch (indep. of conv output) ----
    const int t = threadIdx.x;
    if (t >= 256) return;
    const int b = t >> 4, i0 = t & 15;
    double v = 0.0;
    for (int i = i0; i < 72; i += 16) v += partials[b * 72 + i];
    v += __shfl_down(v, 8, 64);
    v += __shfl_down(v, 4, 64);
    v += __shfl_down(v, 2, 64);
    v += __shfl_down(v, 1, 64);
    if (i0 == 0) inv_xn2[b] = (float)(1.0 / v);
    return;
  }
  const int xcd = bid & 7, q = bid >> 3;     // q in [0,16)
  const int b = xcd + 8 * (q & 1);           // 2 batches per XCD -> xtp[b] L2-resident
  const int rt = q >> 1;                     // [0,8) c'-row tile of 32
  const int tid = threadIdx.x, w = tid >> 6, l = tid & 63, l31 = l & 31, h = l >> 5;
  const unsigned short* xb = xtp + (size_t)b * CHW;

  __shared__ unsigned short tile[32 * 2312];  // [c'_local][m' + pad8]

  // A-frags: W rows 32rt..32rt+31, all K (shared by all waves)
  bf16x8 af[16];
  #pragma unroll
  for (int f = 0; f < 16; ++f)
    af[f] = *(const bf16x8*)(wp + (((size_t)rt * 16 + f) * 64 + l) * 8);
  // bias per accumulator register
  float bcol[16];
  #pragma unroll
  for (int reg = 0; reg < 16; ++reg) {
    const int rowl = (reg & 3) + 8 * (reg >> 2) + 4 * h;
    bcol[reg] = bias[32 * rt + rowl];
  }

  // ---- MFMA phase: wave w covers xtp-mb in [9w, 9w+9) (288 m' each) ----
  for (int i = 0; i < 9; ++i) {
    const int mb = 9 * w + i;
    f32x16 acc;
    #pragma unroll
    for (int r = 0; r < 16; ++r) acc[r] = 0.f;
    #pragma unroll
    for (int f = 0; f < 16; ++f) {
      bf16x8 bv = *(const bf16x8*)(xb + (((size_t)mb * 16 + f) * 64 + l) * 8);
      acc = __builtin_amdgcn_mfma_f32_32x32x16_bf16(af[f], bv, acc, 0, 0, 0);
    }
    #pragma unroll
    for (int reg = 0; reg < 16; ++reg) {
      const int rowl = (reg & 3) + 8 * (reg >> 2) + 4 * h;
      tile[rowl * 2312 + mb * 32 + l31] = f2bf(acc[reg] + bcol[reg]);
    }
  }
  __syncthreads();

  // ---- emission phase: 144 subblocks (kfi in [0,18), cb8 in [0,8)), 18 per wave ----
  unsigned short* tb = trp + (size_t)b * CHW;
  for (int si = 0; si < 18; ++si) {
    const int id = 18 * w + si;
    const int kfi = id >> 3, cb8 = id & 7;
    const int mbase = 288 * rt + 16 * kfi;     // 16-aligned reshaped-row base
    const int mb2 = mbase >> 6, kf = (mbase >> 4) & 3;
    BF8 o;
    #pragma unroll
    for (int j = 0; j < 8; ++j) {
      const int m = mbase + 8 * h + j;         // reshaped row
      const int a = m / 9, s = m - 9 * a;      // c' = a, m' = 256s + c
      o.u[j] = tile[(a - 32 * rt) * 2312 + 256 * s + 32 * cb8 + l31];
    }
    *(bf16x8*)(tb + (size_t)mb2 * 16384 + (((size_t)cb8 * 4 + kf) * 64 + l) * 8) = o.v;
  }
}

// ================= K4: fused v10 — v3 + single-Pl under LB(256,2) (the un-confounded R8) =================
// R10 post-mortem falsified the L2-traffic model (v9 halved traffic, got slower): fused is
// LATENCY-bound; v3's strengths are the bva/bvb prefetch + multi-block barrier overlap.
// This round: keep v3 verbatim (prefetch, LB(256,2)) and shrink ONLY Pl to single-buffered.
// LDS 32K + 17.4K = 50,176 B -> HW can make 3 blocks/CU resident (150.5 KB <= 160 KB) since
// actual VGPR (128) allows 4 waves/SIMD -- occupancy comes from actual resources, not the LB
// hint (R8's LB(256,3) was the confounder: it CAPPED the allocator at 84 -> 701 MB spill).
// Ordering per chunk: S -> bt -> P-in-regs -> NXT -> barrier-A (prev Y-reads done) ->
// Pl write -> barrier-B -> Y. Correctness of this ordering proven in R8.
#define CHUNK_BODY(CH, CUR, NXT)                                                                   \
  {                                                                                                \
    const int ch_ = (CH);                                                                          \
    f32x16 s0, s1;                                                                                 \
    _Pragma("unroll")                                                                              \
    for (int i = 0; i < 16; ++i) { s0[i] = 0.f; s1[i] = 0.f; }                                     \
    _Pragma("unroll")                                                                              \
    for (int f = 0; f < 16; ++f) {                                                                 \
      bf16x8 a0 = *(const bf16x8*)(Af + f * 512 + lane * 8);                                       \
      bf16x8 a1 = *(const bf16x8*)(Af + (16 + f) * 512 + lane * 8);                                \
      s0 = __builtin_amdgcn_mfma_f32_32x32x16_bf16(a0, CUR[f], s0, 0, 0, 0);                       \
      s1 = __builtin_amdgcn_mfma_f32_32x32x16_bf16(a1, CUR[f], s1, 0, 0, 0);                       \
    }                                                                                              \
    bf16x8 bt0[8], bt1[8];                                                                         \
    _Pragma("unroll")                                                                              \
    for (int kk = 0; kk < 8; ++kk) {                                                               \
      const size_t mb_ = 2 * ch_ + (kk >> 2);                                                      \
      bt0[kk] = *(const bf16x8*)(ttb + mb_ * 16384 + ((size_t)((2 * c) * 4 + (kk & 3))) * 512 + lane * 8);     \
      bt1[kk] = *(const bf16x8*)(ttb + mb_ * 16384 + ((size_t)((2 * c + 1) * 4 + (kk & 3))) * 512 + lane * 8); \
    }                                                                                              \
    _Pragma("unroll")                                                                              \
    for (int reg = 0; reg < 16; ++reg) {                                                           \
      float v0 = fmaxf(s0[reg] * inv2, 0.f); s0[reg] = v0 * v0;                                    \
      float v1 = fmaxf(s1[reg] * inv2, 0.f); s1[reg] = v1 * v1;                                    \
    }                                                                                              \
    const int chn_ = (ch_ < 17) ? ch_ + 1 : 17;                                                    \
    const unsigned short* bpn_ = xtb + (size_t)((4 * chn_ + c) * 16) * 512 + lane * 8;             \
    _Pragma("unroll")                                                                              \
    for (int f = 0; f < 16; ++f) NXT[f] = *(const bf16x8*)(bpn_ + f * 512);                        \
    __syncthreads(); /* barrier-A: all waves done reading Pl from previous chunk */                \
    _Pragma("unroll")                                                                              \
    for (int reg = 0; reg < 16; ++reg) {                                                           \
      const int rowp = (reg & 3) + 8 * (reg >> 2) + 4 * h;                                         \
      Pl[rowp][32 * c + l31] = f2bf(s0[reg]);                                                      \
      Pl[32 + rowp][32 * c + l31] = f2bf(s1[reg]);                                                 \
    }                                                                                              \
    __syncthreads(); /* barrier-B: Pl visible */                                                   \
    _Pragma("unroll")                                                                              \
    for (int kk = 0; kk < 8; ++kk) {                                                               \
      bf16x8 pf0 = *(const bf16x8*)&Pl[l31][16 * kk + 8 * h];                                      \
      bf16x8 pf1 = *(const bf16x8*)&Pl[32 + l31][16 * kk + 8 * h];                                 \
      yacc[0][0] = __builtin_amdgcn_mfma_f32_32x32x16_bf16(pf0, bt0[kk], yacc[0][0], 0, 0, 0);     \
      yacc[1][0] = __builtin_amdgcn_mfma_f32_32x32x16_bf16(pf1, bt0[kk], yacc[1][0], 0, 0, 0);     \
      yacc[0][1] = __builtin_amdgcn_mfma_f32_32x32x16_bf16(pf0, bt1[kk], yacc[0][1], 0, 0, 0);     \
      yacc[1][1] = __builtin_amdgcn_mfma_f32_32x32x16_bf16(pf1, bt1[kk], yacc[1][1], 0, 0, 0);     \
    }                                                                                              \
  }

__global__ __launch_bounds__(256, 2) void fused_kernel(const unsigned short* __restrict__ x1p,
                                                       const unsigned short* __restrict__ xtp,
                                                       const unsigned short* __restrict__ trp,
                                                       const float* __restrict__ inv_xn2,
                                                       float* __restrict__ out) {
  const int bid = blockIdx.x;
  const int xcd = bid & 7, j = bid >> 3;     // j in [0,72)
  const int hi = (j >= 36) ? 1 : 0;
  const int b = xcd + 8 * hi;                // one batch per XCD at a time
  const int nt = j - 36 * hi;                // [0,36) n-tile of 64 rows
  const unsigned short* x1b = x1p + (size_t)b * CHW + (size_t)nt * 16384;  // 2 nb blocks
  const unsigned short* xtb = xtp + (size_t)b * CHW;
  const unsigned short* ttb = trp + (size_t)b * CHW;
  float* ob = out + (size_t)b * CHW;
  const float inv2 = inv_xn2[b];

  const int tid = threadIdx.x;
  const int c = tid >> 6, lane = tid & 63;   // wave c = S-col / Y-col group
  const int l31 = lane & 31, h = lane >> 5;

  __shared__ unsigned short Af[16384];       // 2 n-halves x 16 A-frags x 512 shorts (32 KB)
  __shared__ unsigned short Pl[64][136];     // SINGLE-buffered P (17.4 KB) -> LDS 50,176 B

  {  // stage both n-halves' A-frags (coalesced 16B) into LDS once: 2048 uint4
    const uint4* gsrc = (const uint4*)x1b;
    uint4* ldst = (uint4*)Af;
    #pragma unroll
    for (int it = 0; it < 8; ++it) ldst[tid + 256 * it] = gsrc[tid + 256 * it];
  }

  // prologue: chunk 0's S B-frags (issued before the staging barrier; independent of LDS)
  bf16x8 bva[16], bvb[16];
  {
    const unsigned short* bp0 = xtb + (size_t)(c * 16) * 512 + lane * 8;
    #pragma unroll
    for (int f = 0; f < 16; ++f) bva[f] = *(const bf16x8*)(bp0 + f * 512);
  }
  __syncthreads();

  f32x16 yacc[2][2];  // [n-half][cb]
  #pragma unroll
  for (int nh = 0; nh < 2; ++nh)
    #pragma unroll
    for (int cb = 0; cb < 2; ++cb)
      #pragma unroll
      for (int i = 0; i < 16; ++i) yacc[nh][cb][i] = 0.f;

  for (int ci = 0; ci < 9; ++ci) {  // 18 chunks, explicit 2x alternation of bva/bvb (rule #20)
    CHUNK_BODY(2 * ci, bva, bvb)
    CHUNK_BODY(2 * ci + 1, bvb, bva)
  }

  // ---- epilogue: out flat at ob[n*256 + k'] ----
  #pragma unroll
  for (int nh = 0; nh < 2; ++nh)
    #pragma unroll
    for (int cb = 0; cb < 2; ++cb) {
      const int col = 64 * c + 32 * cb + l31;
      #pragma unroll
      for (int reg = 0; reg < 16; ++reg) {
        const int rowp = (reg & 3) + 8 * (reg >> 2) + 4 * h;
        ob[(size_t)(64 * nt + 32 * nh + rowp) * NC + col] = yacc[nh][cb][reg];
      }
    }
}

extern "C" void kernel_launch(void* const* d_in, const int* in_sizes, int n_in,
                              void* d_out, int out_size, void* d_ws, size_t ws_size,
                              hipStream_t stream) {
  const float* x    = (const float*)d_in[0];
  const float* W    = (const float*)d_in[1];
  const float* bias = (const float*)d_in[2];
  float* out = (float*)d_out;

  const size_t SZ = (size_t)NB * CHW * sizeof(unsigned short);  // 18,874,368 B
  double* partials       = (double*)d_ws;                           // 9216 B used
  float* inv_xn2         = (float*)((char*)d_ws + 16384);
  unsigned short* wp     = (unsigned short*)((char*)d_ws + 32768);  // 128 KB
  unsigned short* x1p    = (unsigned short*)((char*)d_ws + 163840);
  unsigned short* xtp    = (unsigned short*)((char*)d_ws + 163840 + SZ);
  unsigned short* trp    = (unsigned short*)((char*)d_ws + 163840 + 3 * SZ);

  prep_kernel<<<3464, 256, 0, stream>>>(x, W, wp, x1p, xtp, partials);
  conv2_kernel<<<129, 512, 0, stream>>>(wp, bias, xtp, trp, partials, inv_xn2);
  fused_kernel<<<576, 256, 0, stream>>>(x1p, xtp, trp, inv_xn2, out);
}